// Round 1
// baseline (2887.726 us; speedup 1.0000x reference)
//
#include <hip/hip_runtime.h>

typedef _Float16 half2_t __attribute__((ext_vector_type(2)));

#define BB 16
#define TT 4096
#define DD 128
#define HH 256

__device__ __forceinline__ float tanh_fast(float x) {
    // tanh(x) = 1 - 2/(exp(2x)+1); exact at both saturations
    float e = __expf(2.0f * x);
    return 1.0f - 2.0f * __builtin_amdgcn_rcpf(e + 1.0f);
}

// ---------------- Phase 1: xh[b,t,h] = sum_d X[b,t,d]*W_x[h,d] + b_x[h] -----
// Register-blocked 8x8 per thread, no LDS (W_x is 128KiB -> L1/L2 resident).
// Block: 256 threads = 16x16, tile 128 rows x 128 cols.
__global__ __launch_bounds__(256) void x2h_gemm(
    const float* __restrict__ inp, const float* __restrict__ Wx,
    const float* __restrict__ bx, float* __restrict__ out)
{
    const int tid = threadIdx.x;
    const int ty = tid >> 4, tx = tid & 15;
    const int row0 = blockIdx.x * 128 + ty * 8;   // flattened (b,t), 65536 rows
    const int col0 = blockIdx.y * 128 + tx * 8;   // h

    float acc[8][8] = {};

    #pragma unroll 2
    for (int k4 = 0; k4 < DD / 4; ++k4) {
        float4 a[8], b[8];
        #pragma unroll
        for (int r = 0; r < 8; ++r)
            a[r] = *(const float4*)&inp[(size_t)(row0 + r) * DD + k4 * 4];
        #pragma unroll
        for (int c = 0; c < 8; ++c)
            b[c] = *(const float4*)&Wx[(size_t)(col0 + c) * DD + k4 * 4];
        #pragma unroll
        for (int r = 0; r < 8; ++r)
            #pragma unroll
            for (int c = 0; c < 8; ++c)
                acc[r][c] += a[r].x * b[c].x + a[r].y * b[c].y
                           + a[r].z * b[c].z + a[r].w * b[c].w;
    }

    float4 bx0 = *(const float4*)&bx[col0];
    float4 bx1 = *(const float4*)&bx[col0 + 4];
    #pragma unroll
    for (int r = 0; r < 8; ++r) {
        float4 o0, o1;
        o0.x = acc[r][0] + bx0.x; o0.y = acc[r][1] + bx0.y;
        o0.z = acc[r][2] + bx0.z; o0.w = acc[r][3] + bx0.w;
        o1.x = acc[r][4] + bx1.x; o1.y = acc[r][5] + bx1.y;
        o1.z = acc[r][6] + bx1.z; o1.w = acc[r][7] + bx1.w;
        *(float4*)&out[(size_t)(row0 + r) * HH + col0]     = o0;
        *(float4*)&out[(size_t)(row0 + r) * HH + col0 + 4] = o1;
    }
}

// ---------------- Phase 2: sequential scan, one workgroup per batch ---------
// Thread j owns output unit j. W_h row j lives in 128 half2 VGPRs.
// h broadcast through LDS (fp16, double-buffered -> one barrier per step).
// xh streamed from d_out (written by phase 1) with 16-step register prefetch;
// h_t overwrites the same location (read-before-write per step).
__global__ __launch_bounds__(256, 1) void rnn_scan(
    const float* __restrict__ Wh, const float* __restrict__ bh,
    float* __restrict__ out)
{
    const int j = threadIdx.x;       // 0..255
    const int b = blockIdx.x;        // batch

    __shared__ __align__(16) _Float16 hA[HH];
    __shared__ __align__(16) _Float16 hB[HH];

    // W_h row j -> fp16 pairs in registers
    half2_t w[HH / 2];
    const float4* wrow = (const float4*)(Wh + (size_t)j * HH);
    #pragma unroll
    for (int k4 = 0; k4 < HH / 4; ++k4) {
        float4 v = wrow[k4];
        w[2 * k4]     = half2_t{(_Float16)v.x, (_Float16)v.y};
        w[2 * k4 + 1] = half2_t{(_Float16)v.z, (_Float16)v.w};
    }
    const float bhv = bh[j];
    hA[j] = (_Float16)0.f;

    float* colp = out + (size_t)b * TT * HH + j;   // column j, stride HH

    constexpr int CH = 16;                          // prefetch chunk (timesteps)
    float xc[CH], xn[CH];
    #pragma unroll
    for (int i = 0; i < CH; ++i) xc[i] = colp[(size_t)i * HH];
    __syncthreads();   // hA (zeros) visible

#define DOT_STEP(SRC, DST, XV, OPTR)                                           \
    {                                                                          \
        const uint4* hp = (const uint4*)(SRC);                                 \
        float a0 = 0.f, a1 = 0.f, a2 = 0.f, a3 = 0.f;                          \
        _Pragma("unroll")                                                      \
        for (int q = 0; q < HH / 8; ++q) {                                     \
            uint4 hv = hp[q];                                                  \
            a0 = __builtin_amdgcn_fdot2(__builtin_bit_cast(half2_t, hv.x),     \
                                        w[4 * q + 0], a0, false);              \
            a1 = __builtin_amdgcn_fdot2(__builtin_bit_cast(half2_t, hv.y),     \
                                        w[4 * q + 1], a1, false);              \
            a2 = __builtin_amdgcn_fdot2(__builtin_bit_cast(half2_t, hv.z),     \
                                        w[4 * q + 2], a2, false);              \
            a3 = __builtin_amdgcn_fdot2(__builtin_bit_cast(half2_t, hv.w),     \
                                        w[4 * q + 3], a3, false);              \
        }                                                                      \
        float z  = (XV) + bhv + ((a0 + a1) + (a2 + a3));                       \
        float hn = tanh_fast(z);                                               \
        *(OPTR) = hn;                                                          \
        (DST)[j] = (_Float16)hn;                                               \
    }                                                                          \
    __syncthreads();

    const int NC = TT / CH;
    for (int c = 0; c < NC; ++c) {
        if (c + 1 < NC) {
            const float* p = colp + (size_t)(c + 1) * CH * HH;
            #pragma unroll
            for (int i = 0; i < CH; ++i) xn[i] = p[(size_t)i * HH];
        }
        float* op = colp + (size_t)c * CH * HH;
        #pragma unroll
        for (int s = 0; s < CH; s += 2) {
            DOT_STEP(hA, hB, xc[s],     op + (size_t)s * HH)
            DOT_STEP(hB, hA, xc[s + 1], op + (size_t)(s + 1) * HH)
        }
        #pragma unroll
        for (int i = 0; i < CH; ++i) xc[i] = xn[i];
    }
#undef DOT_STEP
}

extern "C" void kernel_launch(void* const* d_in, const int* in_sizes, int n_in,
                              void* d_out, int out_size, void* d_ws, size_t ws_size,
                              hipStream_t stream) {
    const float* inp = (const float*)d_in[0];   // [B,T,D]
    const float* Wx  = (const float*)d_in[1];   // [H,D]
    const float* bx  = (const float*)d_in[2];   // [H]
    const float* Wh  = (const float*)d_in[3];   // [H,H]
    const float* bh  = (const float*)d_in[4];   // [H]
    float* out = (float*)d_out;                 // [B,T,H]

    dim3 g1(BB * TT / 128, HH / 128);           // 512 x 2 blocks
    x2h_gemm<<<g1, 256, 0, stream>>>(inp, Wx, bx, out);
    rnn_scan<<<BB, 256, 0, stream>>>(Wh, bh, out);
}

// Round 2
// 1892.524 us; speedup vs baseline: 1.5259x; 1.5259x over previous
//
#include <hip/hip_runtime.h>

typedef _Float16 half2_t __attribute__((ext_vector_type(2)));

#define BB 16
#define TT 4096
#define DD 128
#define HH 256

__device__ __forceinline__ float tanh_fast(float x) {
    // tanh(x) = 1 - 2/(exp(2x)+1); exact at both saturations
    float e = __expf(2.0f * x);
    return 1.0f - 2.0f * __builtin_amdgcn_rcpf(e + 1.0f);
}

// quad-lane butterfly adds via DPP (VALU pipe — NOT ds_swizzle/LDS pipe)
__device__ __forceinline__ float dpp_xor1_add(float a) {
    int v = __builtin_amdgcn_mov_dpp(__builtin_bit_cast(int, a), 0xB1, 0xF, 0xF, true); // quad_perm [1,0,3,2]
    return a + __builtin_bit_cast(float, v);
}
__device__ __forceinline__ float dpp_xor2_add(float a) {
    int v = __builtin_amdgcn_mov_dpp(__builtin_bit_cast(int, a), 0x4E, 0xF, 0xF, true); // quad_perm [2,3,0,1]
    return a + __builtin_bit_cast(float, v);
}

// ---------------- Phase 1: xh[b,t,h] = sum_d X[b,t,d]*W_x[h,d] + b_x[h] -----
__global__ __launch_bounds__(256) void x2h_gemm(
    const float* __restrict__ inp, const float* __restrict__ Wx,
    const float* __restrict__ bx, float* __restrict__ out)
{
    const int tid = threadIdx.x;
    const int ty = tid >> 4, tx = tid & 15;
    const int row0 = blockIdx.x * 128 + ty * 8;   // flattened (b,t)
    const int col0 = blockIdx.y * 128 + tx * 8;   // h

    float acc[8][8] = {};

    #pragma unroll 2
    for (int k4 = 0; k4 < DD / 4; ++k4) {
        float4 a[8], b[8];
        #pragma unroll
        for (int r = 0; r < 8; ++r)
            a[r] = *(const float4*)&inp[(size_t)(row0 + r) * DD + k4 * 4];
        #pragma unroll
        for (int c = 0; c < 8; ++c)
            b[c] = *(const float4*)&Wx[(size_t)(col0 + c) * DD + k4 * 4];
        #pragma unroll
        for (int r = 0; r < 8; ++r)
            #pragma unroll
            for (int c = 0; c < 8; ++c)
                acc[r][c] += a[r].x * b[c].x + a[r].y * b[c].y
                           + a[r].z * b[c].z + a[r].w * b[c].w;
    }

    float4 bx0 = *(const float4*)&bx[col0];
    float4 bx1 = *(const float4*)&bx[col0 + 4];
    #pragma unroll
    for (int r = 0; r < 8; ++r) {
        float4 o0, o1;
        o0.x = acc[r][0] + bx0.x; o0.y = acc[r][1] + bx0.y;
        o0.z = acc[r][2] + bx0.z; o0.w = acc[r][3] + bx0.w;
        o1.x = acc[r][4] + bx1.x; o1.y = acc[r][5] + bx1.y;
        o1.z = acc[r][6] + bx1.z; o1.w = acc[r][7] + bx1.w;
        *(float4*)&out[(size_t)(row0 + r) * HH + col0]     = o0;
        *(float4*)&out[(size_t)(row0 + r) * HH + col0 + 4] = o1;
    }
}

// ---------------- Phase 2: sequential scan, one workgroup per batch ---------
// Split-K x multi-output: lane l = 4*o + r computes partial dots for outputs
// {o, o+64, o+128, o+192} over K-chunk [64r, 64r+64). Each lane reads only
// 128 B of h from LDS per step (8 x ds_read_b128 -> 32 LDS instr/CU/step vs
// 128 before). Quad reduction over r via DPP quad_perm adds (VALU pipe).
// Lane finalizes output jf = o + 64r: tanh, global store, LDS h write.
__global__ __launch_bounds__(256, 1) void rnn_scan(
    const float* __restrict__ Wh, const float* __restrict__ bh,
    float* __restrict__ out)
{
    const int l = threadIdx.x;          // 0..255
    const int o = l >> 2;               // 0..63   output group
    const int r = l & 3;                // 0..3    K-chunk
    const int b = blockIdx.x;           // batch
    const int jf = o + (r << 6);        // finalized output unit

    __shared__ __align__(16) _Float16 hA[HH];
    __shared__ __align__(16) _Float16 hB[HH];

    // W_h rows {o+64s}, cols [64r, 64r+64) -> fp16 pairs in registers
    half2_t w[4][32];
    #pragma unroll
    for (int s = 0; s < 4; ++s) {
        const float4* wp = (const float4*)(Wh + (size_t)(o + (s << 6)) * HH + (r << 6));
        #pragma unroll
        for (int k4 = 0; k4 < 16; ++k4) {
            float4 v = wp[k4];
            w[s][2 * k4]     = half2_t{(_Float16)v.x, (_Float16)v.y};
            w[s][2 * k4 + 1] = half2_t{(_Float16)v.z, (_Float16)v.w};
        }
    }
    const float bhv = bh[jf];
    hA[l] = (_Float16)0.f;

    float* colp = out + (size_t)b * TT * HH + jf;   // xh column jf, stride HH

    constexpr int CH = 16;                          // prefetch chunk (timesteps)
    float xc[CH], xn[CH];
    #pragma unroll
    for (int i = 0; i < CH; ++i) xc[i] = colp[(size_t)i * HH];
    __syncthreads();   // hA (zeros) visible

#define DOT_STEP(SRC, DST, XV, OPTR)                                           \
    {                                                                          \
        const uint4* hp = (const uint4*)(SRC) + (r << 3);                      \
        float a0 = 0.f, a1 = 0.f, a2 = 0.f, a3 = 0.f;                          \
        _Pragma("unroll")                                                      \
        for (int q = 0; q < 8; ++q) {                                          \
            uint4 hv = hp[q];                                                  \
            half2_t h0 = __builtin_bit_cast(half2_t, hv.x);                    \
            half2_t h1 = __builtin_bit_cast(half2_t, hv.y);                    \
            half2_t h2 = __builtin_bit_cast(half2_t, hv.z);                    \
            half2_t h3 = __builtin_bit_cast(half2_t, hv.w);                    \
            a0 = __builtin_amdgcn_fdot2(h0, w[0][4 * q + 0], a0, false);       \
            a0 = __builtin_amdgcn_fdot2(h1, w[0][4 * q + 1], a0, false);       \
            a0 = __builtin_amdgcn_fdot2(h2, w[0][4 * q + 2], a0, false);       \
            a0 = __builtin_amdgcn_fdot2(h3, w[0][4 * q + 3], a0, false);       \
            a1 = __builtin_amdgcn_fdot2(h0, w[1][4 * q + 0], a1, false);       \
            a1 = __builtin_amdgcn_fdot2(h1, w[1][4 * q + 1], a1, false);       \
            a1 = __builtin_amdgcn_fdot2(h2, w[1][4 * q + 2], a1, false);       \
            a1 = __builtin_amdgcn_fdot2(h3, w[1][4 * q + 3], a1, false);       \
            a2 = __builtin_amdgcn_fdot2(h0, w[2][4 * q + 0], a2, false);       \
            a2 = __builtin_amdgcn_fdot2(h1, w[2][4 * q + 1], a2, false);       \
            a2 = __builtin_amdgcn_fdot2(h2, w[2][4 * q + 2], a2, false);       \
            a2 = __builtin_amdgcn_fdot2(h3, w[2][4 * q + 3], a2, false);       \
            a3 = __builtin_amdgcn_fdot2(h0, w[3][4 * q + 0], a3, false);       \
            a3 = __builtin_amdgcn_fdot2(h1, w[3][4 * q + 1], a3, false);       \
            a3 = __builtin_amdgcn_fdot2(h2, w[3][4 * q + 2], a3, false);       \
            a3 = __builtin_amdgcn_fdot2(h3, w[3][4 * q + 3], a3, false);       \
        }                                                                      \
        a0 = dpp_xor2_add(dpp_xor1_add(a0));                                   \
        a1 = dpp_xor2_add(dpp_xor1_add(a1));                                   \
        a2 = dpp_xor2_add(dpp_xor1_add(a2));                                   \
        a3 = dpp_xor2_add(dpp_xor1_add(a3));                                   \
        float av = (r == 0) ? a0 : (r == 1) ? a1 : (r == 2) ? a2 : a3;         \
        float z  = (XV) + bhv + av;                                            \
        float hn = tanh_fast(z);                                               \
        *(OPTR) = hn;                                                          \
        (DST)[jf] = (_Float16)hn;                                              \
    }                                                                          \
    __syncthreads();

    const int NC = TT / CH;
    for (int c = 0; c < NC; ++c) {
        if (c + 1 < NC) {
            const float* p = colp + (size_t)(c + 1) * CH * HH;
            #pragma unroll
            for (int i = 0; i < CH; ++i) xn[i] = p[(size_t)i * HH];
        }
        float* op = colp + (size_t)c * CH * HH;
        #pragma unroll
        for (int s = 0; s < CH; s += 2) {
            DOT_STEP(hA, hB, xc[s],     op + (size_t)s * HH)
            DOT_STEP(hB, hA, xc[s + 1], op + (size_t)(s + 1) * HH)
        }
        #pragma unroll
        for (int i = 0; i < CH; ++i) xc[i] = xn[i];
    }
#undef DOT_STEP
}

extern "C" void kernel_launch(void* const* d_in, const int* in_sizes, int n_in,
                              void* d_out, int out_size, void* d_ws, size_t ws_size,
                              hipStream_t stream) {
    const float* inp = (const float*)d_in[0];   // [B,T,D]
    const float* Wx  = (const float*)d_in[1];   // [H,D]
    const float* bx  = (const float*)d_in[2];   // [H]
    const float* Wh  = (const float*)d_in[3];   // [H,H]
    const float* bh  = (const float*)d_in[4];   // [H]
    float* out = (float*)d_out;                 // [B,T,H]

    dim3 g1(BB * TT / 128, HH / 128);
    x2h_gemm<<<g1, 256, 0, stream>>>(inp, Wx, bx, out);
    rnn_scan<<<BB, 256, 0, stream>>>(Wh, bh, out);
}